// Round 1
// baseline (7642.937 us; speedup 1.0000x reference)
//
#include <hip/hip_runtime.h>
#include <math.h>

#define BB 1024
#define LL 32
#define HH 128
#define NQ 4
#define KPT 32   // HH/NQ k-elements per thread

// Block = 1 sample, 512 threads: tid = q*128 + j.
// Thread (q,j) holds W[k][j] for k in [32q, 32q+32) of all five 128x128
// matrices in registers (160 VGPRs) -> weights are read from global exactly
// once per block instead of once per site (avoids ~327 GB of L2 traffic).
// Carries live in LDS in lattice order; carry[c] is overwritten in place as
// the scan passes column c, so carry[c_prev] is simultaneously the
// horizontal carry and carry[c] the vertical carry.
__global__ __launch_bounds__(512, 1)
void rnn2d_kernel(const int* __restrict__ x,
                  const float* __restrict__ WH,
                  const float* __restrict__ WV,
                  const float* __restrict__ WS0,
                  const float* __restrict__ WS1,
                  const float* __restrict__ Wout,
                  const float* __restrict__ bout,
                  float* __restrict__ out)
{
    __shared__ float carry[LL][2][HH];   // 32 KB: per-column (h0,h1), lattice order
    __shared__ float zbuf[2][HH];        // zeros, stands in for carryH at p==0
    __shared__ float P0[NQ][HH];
    __shared__ float P1[NQ][HH];
    __shared__ float red[2];
    __shared__ int   xrow[LL];
    __shared__ int   xprev[LL];

    const int tid = threadIdx.x;
    const int j   = tid & (HH - 1);
    const int q   = tid >> 7;       // 0..3
    const int k0  = q * KPT;
    const int b   = blockIdx.x;

    // ---- load weight columns into registers (coalesced over j) ----
    float wh0[KPT], wv0[KPT], wh1[KPT], wv1[KPT], ws1r[KPT];
#pragma unroll
    for (int i = 0; i < KPT; ++i) {
        const int k = k0 + i;
        wh0[i]  = WH[k * HH + j];            // WH[0][k][j]
        wv0[i]  = WV[k * HH + j];            // WV[0][k][j]
        wh1[i]  = WH[(HH + k) * HH + j];     // WH[1][k][j]
        wv1[i]  = WV[(HH + k) * HH + j];     // WV[1][k][j]
        ws1r[i] = WS1[k * HH + j];
    }
    const float s0a = WS0[0 * HH + j];   // xH == 0 row
    const float s0b = WS0[1 * HH + j];   // xH == 1 row
    const float s0c = WS0[2 * HH + j];   // xV == 0 row
    const float s0d = WS0[3 * HH + j];   // xV == 1 row
    const float wo  = Wout[j];
    const float bo  = bout[0];

    for (int i = tid; i < LL * 2 * HH; i += 512) ((float*)carry)[i] = 0.0f;
    if (tid < 2 * HH) ((float*)zbuf)[tid] = 0.0f;

    const int* xb = x + b * (LL * LL);
    float total = 0.0f;   // accumulated by tid 0 only

    for (int r = 0; r < LL; ++r) {
        if (tid < LL)           xrow[tid]       = xb[r * LL + tid];
        else if (tid < 2 * LL)  xprev[tid - LL] = (r > 0) ? xb[(r - 1) * LL + (tid - LL)] : 0;
        __syncthreads();   // also covers zero-init on r==0 and WAR on xrow/red

        const int dir = (r & 1) ? -1 : 1;
        for (int p = 0; p < LL; ++p) {
            const int c  = (dir == 1) ? p : (LL - 1 - p);  // lattice col of scan pos p
            const int cp = c - dir;                        // lattice col of scan pos p-1

            const float* cH = (p == 0) ? &zbuf[0][0] : &carry[cp][0][0];
            const float* cV = &carry[c][0][0];

            // ---- depth-0 partial: this thread's 32-k slice of WH0,WV0 ----
            float a0 = 0.f, a1 = 0.f, a2 = 0.f, a3 = 0.f;
#pragma unroll
            for (int i = 0; i < KPT; i += 4) {
                const float4 h4 = *(const float4*)(cH + k0 + i);  // wave-uniform LDS broadcast
                const float4 v4 = *(const float4*)(cV + k0 + i);
                a0 = fmaf(h4.x, wh0[i + 0], a0);
                a1 = fmaf(h4.y, wh0[i + 1], a1);
                a2 = fmaf(h4.z, wh0[i + 2], a2);
                a3 = fmaf(h4.w, wh0[i + 3], a3);
                a0 = fmaf(v4.x, wv0[i + 0], a0);
                a1 = fmaf(v4.y, wv0[i + 1], a1);
                a2 = fmaf(v4.z, wv0[i + 2], a2);
                a3 = fmaf(v4.w, wv0[i + 3], a3);
            }
            P0[q][j] = (a0 + a1) + (a2 + a3);
            __syncthreads();   // A: partials visible

            if (q == 0) {
                float s = (P0[0][j] + P0[1][j]) + (P0[2][j] + P0[3][j]);
                if (p > 0) s += (xrow[cp] == 0) ? s0a : s0b;   // xH one-hot @ WS0[0:2]
                if (r > 0) s += (xprev[c] == 0) ? s0c : s0d;   // xV one-hot @ WS0[2:4]
                s = (s > 0.f) ? s : expm1f(s);                 // elu
                carry[c][0][j] = s;                            // h0 (replaces old cV0 post-use)
            }
            __syncthreads();   // B: h0 broadcast

            // ---- depth-1 partial: WH1,WV1 on old carries + WS1 on fresh h0 ----
            const float* cH1 = cH + HH;
            const float* cV1 = cV + HH;
            const float* h0v = &carry[c][0][0];
            a0 = a1 = a2 = a3 = 0.f;
#pragma unroll
            for (int i = 0; i < KPT; i += 4) {
                const float4 h4 = *(const float4*)(cH1 + k0 + i);
                const float4 v4 = *(const float4*)(cV1 + k0 + i);
                const float4 s4 = *(const float4*)(h0v + k0 + i);
                a0 = fmaf(h4.x, wh1[i + 0], a0);
                a1 = fmaf(h4.y, wh1[i + 1], a1);
                a2 = fmaf(h4.z, wh1[i + 2], a2);
                a3 = fmaf(h4.w, wh1[i + 3], a3);
                a0 = fmaf(v4.x, wv1[i + 0], a0);
                a1 = fmaf(v4.y, wv1[i + 1], a1);
                a2 = fmaf(v4.z, wv1[i + 2], a2);
                a3 = fmaf(v4.w, wv1[i + 3], a3);
                a0 = fmaf(s4.x, ws1r[i + 0], a0);
                a1 = fmaf(s4.y, ws1r[i + 1], a1);
                a2 = fmaf(s4.z, ws1r[i + 2], a2);
                a3 = fmaf(s4.w, ws1r[i + 3], a3);
            }
            P1[q][j] = (a0 + a1) + (a2 + a3);
            __syncthreads();   // C: partials visible

            if (q == 0) {
                float s = (P1[0][j] + P1[1][j]) + (P1[2][j] + P1[3][j]);
                s = (s > 0.f) ? s : expm1f(s);                 // elu -> h1
                carry[c][1][j] = s;
                float g = s * wo;                              // output-head partial
#pragma unroll
                for (int off = 32; off > 0; off >>= 1)
                    g += __shfl_down(g, off, 64);
                if ((tid & 63) == 0) red[tid >> 6] = g;        // waves 0,1 -> red[0],red[1]
            }
            __syncthreads();   // D: h1 + head reduction visible

            if (tid == 0) {
                const float t  = red[0] + red[1] + bo;
                const float sp = fmaxf(t, 0.f) + log1pf(expf(-fabsf(t)));  // softplus
                total += 0.5f * (((xrow[c] == 1) ? t : 0.f) - sp);         // 0.5*log_softmax pick
            }
        }
        __syncthreads();   // protect xrow/xprev before next-row staging
    }
    if (tid == 0) out[b] = total;
}

extern "C" void kernel_launch(void* const* d_in, const int* in_sizes, int n_in,
                              void* d_out, int out_size, void* d_ws, size_t ws_size,
                              hipStream_t stream) {
    rnn2d_kernel<<<dim3(BB), dim3(512), 0, stream>>>(
        (const int*)  d_in[0],   // x      (B,L,L) int32
        (const float*)d_in[1],   // WH     (2,128,128)
        (const float*)d_in[2],   // WV     (2,128,128)
        (const float*)d_in[3],   // WS0    (4,128)
        (const float*)d_in[4],   // WS1    (128,128)
        (const float*)d_in[5],   // Wout   (128,1)
        (const float*)d_in[6],   // bout   (1,)
        (float*)d_out);          // (B,) fp32
}

// Round 3
// 4504.182 us; speedup vs baseline: 1.6969x; 1.6969x over previous
//
#include <hip/hip_runtime.h>
#include <math.h>

#define LL  32
#define HH  128
#define NQ  4     // k-slice groups
#define NS  4     // samples per block
#define KPT 32    // HH/NQ k-elements per thread

// Block = 4 samples, 512 threads: tid = q*128 + j.
// Thread (q,j) holds column j of k-slice [32q,32q+32) of all five 128x128
// matrices in registers (160 VGPRs), kept live via asm keep-alive so the
// allocator cannot rematerialize the global loads (round-1 failure mode:
// VGPR=120 -> weights re-fetched from L2 every site -> ~335 GB L2-bound).
// The 4 samples advance through the boustrophedon scan in lockstep, sharing
// the weight registers and the barriers; reduce phases map thread (q,j) to
// sample q so all 512 threads stay busy.
// Carries live in LDS in lattice order; carry[s][c] is overwritten in place
// as the scan passes column c (old value = vertical carry, new = horizontal).
__global__ __launch_bounds__(512, 2)
void rnn2d_kernel(const int* __restrict__ x,
                  const float* __restrict__ WH,
                  const float* __restrict__ WV,
                  const float* __restrict__ WS0,
                  const float* __restrict__ WS1,
                  const float* __restrict__ Wout,
                  const float* __restrict__ bout,
                  float* __restrict__ out)
{
    __shared__ float carry[NS][LL][2][HH];   // 128 KB
    __shared__ float Pa[NS][NQ][HH];         // 8 KB: depth-0 partials, reused for WS1 partials
    __shared__ float Pb[NS][NQ][HH];         // 8 KB: depth-1 H/V partials
    __shared__ float zbuf[2][HH];            // zeros, stands in for carryH at p==0
    __shared__ float red[NS][2];
    __shared__ int   xrow[NS][LL];
    __shared__ int   xprev[NS][LL];

    const int tid = threadIdx.x;
    const int j   = tid & (HH - 1);
    const int q   = tid >> 7;       // 0..3
    const int k0  = q * KPT;
    const int b4  = blockIdx.x * NS;

    // ---- weight columns into registers (coalesced over j, one-time) ----
    float wh0[KPT], wv0[KPT], wh1[KPT], wv1[KPT], ws1r[KPT];
#pragma unroll
    for (int i = 0; i < KPT; ++i) {
        const int k = k0 + i;
        wh0[i]  = WH[k * HH + j];
        wv0[i]  = WV[k * HH + j];
        wh1[i]  = WH[(HH + k) * HH + j];
        wv1[i]  = WV[(HH + k) * HH + j];
        ws1r[i] = WS1[k * HH + j];
    }
    // Pin as opaque register values: prevents rematerialization of the loads.
#pragma unroll
    for (int i = 0; i < KPT; ++i)
        asm volatile("" : "+v"(wh0[i]), "+v"(wv0[i]), "+v"(wh1[i]),
                          "+v"(wv1[i]), "+v"(ws1r[i]));

    const float s0a = WS0[0 * HH + j];   // xH == 0
    const float s0b = WS0[1 * HH + j];   // xH == 1
    const float s0c = WS0[2 * HH + j];   // xV == 0
    const float s0d = WS0[3 * HH + j];   // xV == 1
    const float wo  = Wout[j];
    const float bo  = bout[0];

    for (int i = tid; i < NS * LL * 2 * HH; i += 512) ((float*)carry)[i] = 0.0f;
    if (tid < 2 * HH) ((float*)zbuf)[tid] = 0.0f;

    float total = 0.0f;   // sample-q sum, held by the j==0 thread of group q

#pragma unroll 1
    for (int r = 0; r < LL; ++r) {
        if (tid < NS * LL) {
            xrow[tid >> 5][tid & 31] = x[(b4 + (tid >> 5)) * (LL * LL) + r * LL + (tid & 31)];
        } else if (tid < 2 * NS * LL) {
            const int t2 = tid - NS * LL;
            xprev[t2 >> 5][t2 & 31] =
                (r > 0) ? x[(b4 + (t2 >> 5)) * (LL * LL) + (r - 1) * LL + (t2 & 31)] : 0;
        }
        __syncthreads();   // staging visible (also covers r==0 zero-init)

        const int dir = (r & 1) ? -1 : 1;
#pragma unroll 1
        for (int p = 0; p < LL; ++p) {
            const int c  = (dir == 1) ? p : (LL - 1 - p);
            const int cp = c - dir;

            // ---- phase 0: depth-0 H/V + depth-1 H/V partials (all carries old) ----
#pragma unroll
            for (int smp = 0; smp < NS; ++smp) {
                const float* cH = (p == 0) ? &zbuf[0][0] : &carry[smp][cp][0][0];
                const float* cV = &carry[smp][c][0][0];
                float a0 = 0.f, a1 = 0.f, a2 = 0.f, a3 = 0.f;   // depth 0
                float e0 = 0.f, e1 = 0.f, e2 = 0.f, e3 = 0.f;   // depth 1 (H/V part)
#pragma unroll
                for (int i = 0; i < KPT; i += 4) {
                    const float4 h0 = *(const float4*)(cH + k0 + i);        // uniform -> broadcast
                    const float4 v0 = *(const float4*)(cV + k0 + i);
                    const float4 h1 = *(const float4*)(cH + HH + k0 + i);
                    const float4 v1 = *(const float4*)(cV + HH + k0 + i);
                    a0 = fmaf(h0.x, wh0[i + 0], a0);
                    a1 = fmaf(h0.y, wh0[i + 1], a1);
                    a2 = fmaf(h0.z, wh0[i + 2], a2);
                    a3 = fmaf(h0.w, wh0[i + 3], a3);
                    a0 = fmaf(v0.x, wv0[i + 0], a0);
                    a1 = fmaf(v0.y, wv0[i + 1], a1);
                    a2 = fmaf(v0.z, wv0[i + 2], a2);
                    a3 = fmaf(v0.w, wv0[i + 3], a3);
                    e0 = fmaf(h1.x, wh1[i + 0], e0);
                    e1 = fmaf(h1.y, wh1[i + 1], e1);
                    e2 = fmaf(h1.z, wh1[i + 2], e2);
                    e3 = fmaf(h1.w, wh1[i + 3], e3);
                    e0 = fmaf(v1.x, wv1[i + 0], e0);
                    e1 = fmaf(v1.y, wv1[i + 1], e1);
                    e2 = fmaf(v1.z, wv1[i + 2], e2);
                    e3 = fmaf(v1.w, wv1[i + 3], e3);
                }
                Pa[smp][q][j] = (a0 + a1) + (a2 + a3);
                Pb[smp][q][j] = (e0 + e1) + (e2 + e3);
            }
            __syncthreads();   // A: partials visible

            // ---- reduce 0: thread (q,j) finalizes h0 of sample q ----
            {
                float s = (Pa[q][0][j] + Pa[q][1][j]) + (Pa[q][2][j] + Pa[q][3][j]);
                if (p > 0) s += (xrow[q][cp] == 0) ? s0a : s0b;
                if (r > 0) s += (xprev[q][c] == 0) ? s0c : s0d;
                s = (s > 0.f) ? s : expm1f(s);                 // elu
                carry[q][c][0][j] = s;                         // h0 (old cV0 already consumed)
            }
            __syncthreads();   // B: h0 broadcast

            // ---- phase 1: WS1 @ h0 partials ----
#pragma unroll
            for (int smp = 0; smp < NS; ++smp) {
                const float* h0p = &carry[smp][c][0][0];
                float a0 = 0.f, a1 = 0.f, a2 = 0.f, a3 = 0.f;
#pragma unroll
                for (int i = 0; i < KPT; i += 4) {
                    const float4 s4 = *(const float4*)(h0p + k0 + i);
                    a0 = fmaf(s4.x, ws1r[i + 0], a0);
                    a1 = fmaf(s4.y, ws1r[i + 1], a1);
                    a2 = fmaf(s4.z, ws1r[i + 2], a2);
                    a3 = fmaf(s4.w, ws1r[i + 3], a3);
                }
                Pa[smp][q][j] = (a0 + a1) + (a2 + a3);   // reuse Pa (P0 consumed at bar A..B)
            }
            __syncthreads();   // C: WS1 partials visible

            // ---- reduce 1: h1, output head ----
            int xc = 0;
            {
                float t = (Pa[q][0][j] + Pa[q][1][j]) + (Pa[q][2][j] + Pa[q][3][j])
                        + (Pb[q][0][j] + Pb[q][1][j]) + (Pb[q][2][j] + Pb[q][3][j]);
                t = (t > 0.f) ? t : expm1f(t);                 // elu -> h1
                carry[q][c][1][j] = t;
                float g = t * wo;
#pragma unroll
                for (int off = 32; off > 0; off >>= 1)
                    g += __shfl_down(g, off, 64);
                if ((j & 63) == 0) red[q][j >> 6] = g;         // two waves per sample
                xc = xrow[q][c];   // pre-read: avoids race with next-row staging after bar D
            }
            __syncthreads();   // D: h1 + head partials visible

            if (j == 0) {
                const float t  = red[q][0] + red[q][1] + bo;
                const float sp = fmaxf(t, 0.f) + log1pf(expf(-fabsf(t)));   // softplus
                total += 0.5f * (((xc == 1) ? t : 0.f) - sp);               // 0.5*log_softmax pick
            }
        }
    }
    if (j == 0) out[b4 + q] = total;
}

extern "C" void kernel_launch(void* const* d_in, const int* in_sizes, int n_in,
                              void* d_out, int out_size, void* d_ws, size_t ws_size,
                              hipStream_t stream) {
    rnn2d_kernel<<<dim3(1024 / NS), dim3(512), 0, stream>>>(
        (const int*)  d_in[0],   // x      (B,L,L) int32
        (const float*)d_in[1],   // WH     (2,128,128)
        (const float*)d_in[2],   // WV     (2,128,128)
        (const float*)d_in[3],   // WS0    (4,128)
        (const float*)d_in[4],   // WS1    (128,128)
        (const float*)d_in[5],   // Wout   (128,1)
        (const float*)d_in[6],   // bout   (1,)
        (float*)d_out);          // (B,) fp32
}